// Round 3
// baseline (737.238 us; speedup 1.0000x reference)
//
#include <hip/hip_runtime.h>
#include <hip/hip_bf16.h>
#include <hip/hip_fp16.h>
#include <math.h>

#define N_NODES 50000
#define F_IN 256
#define F_OUT 128
#define NBUK ((N_NODES + 255) >> 8)   // 196 buckets of 256 dsts

typedef __attribute__((ext_vector_type(8))) short bf16x8;
typedef __attribute__((ext_vector_type(4))) float f32x4;
typedef _Float16 h2 __attribute__((ext_vector_type(2)));

static __device__ __forceinline__ h2 u2h2(unsigned u) {
    union { unsigned u; h2 h; } x; x.u = u; return x.h;
}
static __device__ __forceinline__ short f2bf(float f) {
    unsigned u = __float_as_uint(f);
    unsigned r = (u + 0x7FFFu + ((u >> 16) & 1u)) >> 16;  // RNE
    return (short)r;
}
static __device__ __forceinline__ float fast_tanh(float x) {
    float e = __expf(2.0f * x);
    return 1.0f - 2.0f / (e + 1.0f);
}

// ---------------------------------------------------------------------------
// K1: detect int64 vs int32 edge_index layout.
__global__ __launch_bounds__(64) void k_detect(const int* __restrict__ ei,
                                               int* __restrict__ flag) {
    if (threadIdx.x == 0) {
        int orv = 0;
        for (int i = 0; i < 64; i++) orv |= ei[2 * i + 1];
        flag[0] = (orv == 0) ? 1 : 0;  // 1 => int64
    }
}

// K2: decode + pack {src | dstlow<<16 | bucket<<24, w_fp16} + dst histogram.
__global__ __launch_bounds__(256) void k_hist(const void* __restrict__ ei,
                                              const float* __restrict__ ew,
                                              const int* __restrict__ flag,
                                              int2* __restrict__ pk,
                                              int* __restrict__ counts, int E) {
    int e = blockIdx.x * 256 + threadIdx.x;
    if (e >= E) return;
    int s, d;
    if (flag[0]) {
        const long long* p = (const long long*)ei;
        s = (int)p[e];
        d = (int)p[(size_t)E + e];
    } else {
        const int* p = (const int*)ei;
        s = p[e];
        d = p[(size_t)E + e];
    }
    unsigned wh = __half_as_ushort(__float2half(ew[e]));
    pk[e] = make_int2(s | ((d & 255) << 16) | ((d >> 8) << 24), (int)wh);
    atomicAdd(&counts[d], 1);
}

// K3: per-block scan.
__global__ __launch_bounds__(256) void k_scan1(const int* __restrict__ counts,
                                               int* __restrict__ rstart,
                                               int* __restrict__ bsums, int n) {
    __shared__ int sh[256];
    int t = threadIdx.x;
    int i = blockIdx.x * 256 + t;
    int c = (i < n) ? counts[i] : 0;
    int val = c;
    sh[t] = val;
    __syncthreads();
    for (int off = 1; off < 256; off <<= 1) {
        int x = (t >= off) ? sh[t - off] : 0;
        __syncthreads();
        val += x;
        sh[t] = val;
        __syncthreads();
    }
    if (i < n) rstart[i] = val - c;
    if (t == 255) bsums[blockIdx.x] = val;
}

// K4: scan of block sums (NB <= 256).
__global__ __launch_bounds__(256) void k_scan2(const int* __restrict__ bsums,
                                               int* __restrict__ boffs, int n) {
    __shared__ int sh[256];
    int t = threadIdx.x;
    int c = (t < n) ? bsums[t] : 0;
    int val = c;
    sh[t] = val;
    __syncthreads();
    for (int off = 1; off < 256; off <<= 1) {
        int x = (t >= off) ? sh[t - off] : 0;
        __syncthreads();
        val += x;
        sh[t] = val;
        __syncthreads();
    }
    if (t < n) boffs[t] = val - c;
}

// K5: finalize row_start; bucket cursor = rstart[bucket<<8] (same thread, no race).
__global__ __launch_bounds__(256) void k_finish(int* __restrict__ rstart,
                                                const int* __restrict__ boffs,
                                                int* __restrict__ bcursor,
                                                int n, int E) {
    int i = blockIdx.x * 256 + threadIdx.x;
    if (i < n) {
        int v = rstart[i] + boffs[i >> 8];
        rstart[i] = v;
        if ((i & 255) == 0) bcursor[i >> 8] = v;
    }
    if (blockIdx.x == 0 && threadIdx.x == 0) rstart[n] = E;
}

// K6a: partition edges into per-bucket contiguous regions of `stage`.
__global__ __launch_bounds__(256) void k_partA(const int2* __restrict__ pk,
                                               int* __restrict__ bcursor,
                                               int2* __restrict__ stage, int E) {
    int e = blockIdx.x * 256 + threadIdx.x;
    if (e >= E) return;
    int2 v = pk[e];
    int b = ((unsigned)v.x) >> 24;
    int pos = atomicAdd(&bcursor[b], 1);
    stage[pos] = v;
}

// K6b: one block per bucket; LDS rank atomics -> exact CSR position.
// All writes land in the block's own ~32KB window (single-XCD L2 locality).
__global__ __launch_bounds__(256) void k_partB(const int* __restrict__ rstart,
                                               const int2* __restrict__ stage,
                                               int2* __restrict__ ep) {
    __shared__ int lcnt[256];
    __shared__ int lrs[256];
    int b = blockIdx.x, t = threadIdx.x;
    int dst0 = b << 8;
    int dst1 = min(dst0 + 256, N_NODES);
    lcnt[t] = 0;
    lrs[t] = rstart[min(dst0 + t, N_NODES)];
    __syncthreads();
    int base = rstart[dst0];
    int cnt = rstart[dst1] - base;
    for (int i = t; i < cnt; i += 256) {
        int2 v = stage[base + i];
        int dl = (v.x >> 16) & 255;
        int r = atomicAdd(&lcnt[dl], 1);
        ep[lrs[dl] + r] = make_int2(v.x & 0xFFFF, v.y);
    }
}

// ---------------------------------------------------------------------------
// K7: W[256][128] fp32 -> Wt[128][256] bf16 (transposed).
__global__ __launch_bounds__(256) void k_wconv(const float* __restrict__ W,
                                               short* __restrict__ Wt) {
    int id = blockIdx.x * 256 + threadIdx.x;
    if (id >= F_IN * F_OUT) return;
    int n = id >> 8;
    int k = id & 255;
    Wt[id] = f2bf(W[(size_t)k * F_OUT + n]);
}

// K8: H[M,128] = tanh(A[M,256] @ W) via bf16 MFMA, output fp16.
__global__ __launch_bounds__(256) void k_gemm_mfma(const float* __restrict__ A,
                                                   const short* __restrict__ Wt,
                                                   __half* __restrict__ H, int M) {
    int wave = threadIdx.x >> 6;
    int lane = threadIdx.x & 63;
    int lm = lane & 15;
    int kgrp = lane >> 4;
    int m = blockIdx.x * 64 + wave * 16 + lm;
    int am = (m < M) ? m : (M - 1);
    const float* arow = A + (size_t)am * F_IN + kgrp * 8;

    f32x4 acc[8] = {};

    for (int k0 = 0; k0 < F_IN; k0 += 32) {
        float4 a0 = *(const float4*)(arow + k0);
        float4 a1 = *(const float4*)(arow + k0 + 4);
        bf16x8 af;
        af[0] = f2bf(a0.x); af[1] = f2bf(a0.y);
        af[2] = f2bf(a0.z); af[3] = f2bf(a0.w);
        af[4] = f2bf(a1.x); af[5] = f2bf(a1.y);
        af[6] = f2bf(a1.z); af[7] = f2bf(a1.w);
        #pragma unroll
        for (int j = 0; j < 8; j++) {
            int col = j * 16 + lm;
            bf16x8 bf = *(const bf16x8*)(Wt + (size_t)col * F_IN + k0 + kgrp * 8);
            acc[j] = __builtin_amdgcn_mfma_f32_16x16x32_bf16(af, bf, acc[j], 0, 0, 0);
        }
    }

    int rbase = blockIdx.x * 64 + wave * 16 + kgrp * 4;
    #pragma unroll
    for (int j = 0; j < 8; j++) {
        #pragma unroll
        for (int jj = 0; jj < 4; jj++) {
            int r = rbase + jj;
            if (r < M)
                H[(size_t)r * F_OUT + j * 16 + lm] =
                    __float2half(fast_tanh(acc[j][jj]));
        }
    }
}

// ---------------------------------------------------------------------------
// K9: SPMM hop. One wave handles TWO nodes (interleaved gathers for ILP);
// lane owns cols {2*lane, 2*lane+1}. Per edge: 2 readlane + 2 v_dot2_f32_f16.
// ep.y holds w as fp16 in low 16 bits: (w,0) selects col-even, (0,w) col-odd.
__global__ __launch_bounds__(256) void k_hop(const int* __restrict__ rstart,
                                             const int2* __restrict__ ep,
                                             const unsigned* __restrict__ xin,
                                             void* __restrict__ xoutv,
                                             const float* __restrict__ bias,
                                             int last) {
    int pair = blockIdx.x * 4 + (threadIdx.x >> 6);
    int widA = pair * 2;
    if (widA >= N_NODES) return;
    int widB = widA + 1;
    bool hasB = widB < N_NODES;
    int lane = threadIdx.x & 63;
    int sA = rstart[widA], eA = rstart[widA + 1];
    int sB = hasB ? rstart[widB] : 0;
    int eB = hasB ? rstart[widB + 1] : 0;
    float axA = 0.f, ayA = 0.f, axB = 0.f, ayB = 0.f;

#define EDGE(ev, j, ax, ay) {                                              \
        int sj = __builtin_amdgcn_readlane((ev).x, (j));                   \
        int wj = __builtin_amdgcn_readlane((ev).y, (j));                   \
        unsigned hv = xin[(size_t)sj * 64 + lane];                         \
        h2 h = u2h2(hv);                                                   \
        ax = __builtin_amdgcn_fdot2(h, u2h2((unsigned)wj), ax, false);     \
        ay = __builtin_amdgcn_fdot2(h, u2h2(((unsigned)wj) << 16), ay, false); }

    while (sA < eA || sB < eB) {
        int nA = eA - sA; nA = (nA > 64) ? 64 : (nA < 0 ? 0 : nA);
        int nB = eB - sB; nB = (nB > 64) ? 64 : (nB < 0 ? 0 : nB);
        int2 evA = (lane < nA) ? ep[sA + lane] : make_int2(0, 0);
        int2 evB = (lane < nB) ? ep[sB + lane] : make_int2(0, 0);
        int m = (nA < nB) ? nA : nB;
        int i = 0;
        for (; i + 2 <= m; i += 2) {
            EDGE(evA, i, axA, ayA)
            EDGE(evB, i, axB, ayB)
            EDGE(evA, i + 1, axA, ayA)
            EDGE(evB, i + 1, axB, ayB)
        }
        if (i < m) { EDGE(evA, i, axA, ayA) EDGE(evB, i, axB, ayB) i++; }
        for (int j = i; j < nA; j++) EDGE(evA, j, axA, ayA)
        for (int j = i; j < nB; j++) EDGE(evB, j, axB, ayB)
        sA += nA;
        sB += nB;
    }
#undef EDGE

    if (last) {
        float bx = bias[2 * lane], by = bias[2 * lane + 1];
        float2* o = (float2*)xoutv;
        o[(size_t)widA * 64 + lane] = make_float2(axA + bx, ayA + by);
        if (hasB) o[(size_t)widB * 64 + lane] = make_float2(axB + bx, ayB + by);
    } else {
        __half2* o = (__half2*)xoutv;
        o[(size_t)widA * 64 + lane] = __floats2half2_rn(axA, ayA);
        if (hasB) o[(size_t)widB * 64 + lane] = __floats2half2_rn(axB, ayB);
    }
}

// ---------------------------------------------------------------------------
extern "C" void kernel_launch(void* const* d_in, const int* in_sizes, int n_in,
                              void* d_out, int out_size, void* d_ws, size_t ws_size,
                              hipStream_t stream) {
    const float* features = (const float*)d_in[0];
    const float* weight   = (const float*)d_in[1];
    const float* bias     = (const float*)d_in[2];
    const void*  edge_idx = d_in[3];
    const float* edge_w   = (const float*)d_in[4];
    int E = in_sizes[4];
    float* out = (float*)d_out;

    char* ws = (char*)d_ws;
    size_t off = 0;
    auto alloc = [&](size_t bytes) -> void* {
        void* p = ws + off;
        off = (off + bytes + 255) & ~(size_t)255;
        return p;
    };
    int*    flag    = (int*)alloc(4);
    int*    counts  = (int*)alloc((size_t)N_NODES * 4);
    int*    rstart  = (int*)alloc((size_t)(N_NODES + 1) * 4);
    int*    bsums   = (int*)alloc(256 * 4);
    int*    boffs   = (int*)alloc(256 * 4);
    int*    bcursor = (int*)alloc(256 * 4);
    int2*   pk      = (int2*)alloc((size_t)E * 8);
    int2*   stage   = (int2*)alloc((size_t)E * 8);
    int2*   ep      = (int2*)alloc((size_t)E * 8);
    short*  Wt      = (short*)alloc((size_t)F_IN * F_OUT * 2);
    __half* H0      = (__half*)alloc((size_t)N_NODES * F_OUT * 2);
    __half* H1      = (__half*)alloc((size_t)N_NODES * F_OUT * 2);

    hipMemsetAsync(counts, 0, (size_t)N_NODES * 4, stream);

    k_detect<<<1, 64, 0, stream>>>((const int*)edge_idx, flag);
    k_hist<<<(E + 255) / 256, 256, 0, stream>>>(edge_idx, edge_w, flag, pk,
                                                counts, E);
    int NB = (N_NODES + 255) / 256;  // 196
    k_scan1<<<NB, 256, 0, stream>>>(counts, rstart, bsums, N_NODES);
    k_scan2<<<1, 256, 0, stream>>>(bsums, boffs, NB);
    k_finish<<<NB, 256, 0, stream>>>(rstart, boffs, bcursor, N_NODES, E);
    k_partA<<<(E + 255) / 256, 256, 0, stream>>>(pk, bcursor, stage, E);
    k_partB<<<NBUK, 256, 0, stream>>>(rstart, stage, ep);

    // H0 = tanh(features @ weight)  [bf16 MFMA, fp16 out]
    k_wconv<<<(F_IN * F_OUT + 255) / 256, 256, 0, stream>>>(weight, Wt);
    k_gemm_mfma<<<(N_NODES + 63) / 64, 256, 0, stream>>>(features, Wt, H0,
                                                         N_NODES);

    // 3 SPMM hops; last fuses +bias, writes fp32 d_out
    int hop_blocks = (25000 + 3) / 4;  // ceil(N/2) pairs, 4 waves/block
    k_hop<<<hop_blocks, 256, 0, stream>>>(rstart, ep, (const unsigned*)H0, H1,
                                          bias, 0);
    k_hop<<<hop_blocks, 256, 0, stream>>>(rstart, ep, (const unsigned*)H1, H0,
                                          bias, 0);
    k_hop<<<hop_blocks, 256, 0, stream>>>(rstart, ep, (const unsigned*)H0, out,
                                          bias, 1);
}

// Round 4
// 295.262 us; speedup vs baseline: 2.4969x; 2.4969x over previous
//
#include <hip/hip_runtime.h>
#include <hip/hip_bf16.h>
#include <hip/hip_fp16.h>
#include <math.h>

#define N_NODES 50000
#define F_IN 256
#define F_OUT 128
#define NBUK ((N_NODES + 255) >> 8)   // 196 buckets of 256 dsts

typedef __attribute__((ext_vector_type(8))) short bf16x8;
typedef __attribute__((ext_vector_type(4))) float f32x4;
typedef _Float16 h2 __attribute__((ext_vector_type(2)));

static __device__ __forceinline__ h2 u2h2(unsigned u) {
    union { unsigned u; h2 h; } x; x.u = u; return x.h;
}
static __device__ __forceinline__ short f2bf(float f) {
    unsigned u = __float_as_uint(f);
    unsigned r = (u + 0x7FFFu + ((u >> 16) & 1u)) >> 16;  // RNE
    return (short)r;
}
static __device__ __forceinline__ float fast_tanh(float x) {
    float e = __expf(2.0f * x);
    return 1.0f - 2.0f / (e + 1.0f);
}

// ---------------------------------------------------------------------------
// K1: detect int64 vs int32 edge_index layout.
__global__ __launch_bounds__(64) void k_detect(const int* __restrict__ ei,
                                               int* __restrict__ flag) {
    if (threadIdx.x == 0) {
        int orv = 0;
        for (int i = 0; i < 64; i++) orv |= ei[2 * i + 1];
        flag[0] = (orv == 0) ? 1 : 0;  // 1 => int64
    }
}

// K2: decode + pack {src | dstlow<<16 | bucket<<24, w_fp16} + dst histogram.
__global__ __launch_bounds__(256) void k_hist(const void* __restrict__ ei,
                                              const float* __restrict__ ew,
                                              const int* __restrict__ flag,
                                              int2* __restrict__ pk,
                                              int* __restrict__ counts, int E) {
    int e = blockIdx.x * 256 + threadIdx.x;
    if (e >= E) return;
    int s, d;
    if (flag[0]) {
        const long long* p = (const long long*)ei;
        s = (int)p[e];
        d = (int)p[(size_t)E + e];
    } else {
        const int* p = (const int*)ei;
        s = p[e];
        d = p[(size_t)E + e];
    }
    unsigned wh = __half_as_ushort(__float2half(ew[e]));
    pk[e] = make_int2(s | ((d & 255) << 16) | ((d >> 8) << 24), (int)wh);
    atomicAdd(&counts[d], 1);
}

// K3: per-block scan.
__global__ __launch_bounds__(256) void k_scan1(const int* __restrict__ counts,
                                               int* __restrict__ rstart,
                                               int* __restrict__ bsums, int n) {
    __shared__ int sh[256];
    int t = threadIdx.x;
    int i = blockIdx.x * 256 + t;
    int c = (i < n) ? counts[i] : 0;
    int val = c;
    sh[t] = val;
    __syncthreads();
    for (int off = 1; off < 256; off <<= 1) {
        int x = (t >= off) ? sh[t - off] : 0;
        __syncthreads();
        val += x;
        sh[t] = val;
        __syncthreads();
    }
    if (i < n) rstart[i] = val - c;
    if (t == 255) bsums[blockIdx.x] = val;
}

// K4: scan of block sums (NB <= 256).
__global__ __launch_bounds__(256) void k_scan2(const int* __restrict__ bsums,
                                               int* __restrict__ boffs, int n) {
    __shared__ int sh[256];
    int t = threadIdx.x;
    int c = (t < n) ? bsums[t] : 0;
    int val = c;
    sh[t] = val;
    __syncthreads();
    for (int off = 1; off < 256; off <<= 1) {
        int x = (t >= off) ? sh[t - off] : 0;
        __syncthreads();
        val += x;
        sh[t] = val;
        __syncthreads();
    }
    if (t < n) boffs[t] = val - c;
}

// K5: finalize row_start; bucket cursor (padded: 1 per 64B line).
__global__ __launch_bounds__(256) void k_finish(int* __restrict__ rstart,
                                                const int* __restrict__ boffs,
                                                int* __restrict__ bcursor,
                                                int n, int E) {
    int i = blockIdx.x * 256 + threadIdx.x;
    if (i < n) {
        int v = rstart[i] + boffs[i >> 8];
        rstart[i] = v;
        if ((i & 255) == 0) bcursor[(i >> 8) << 4] = v;
    }
    if (blockIdx.x == 0 && threadIdx.x == 0) rstart[n] = E;
}

// K6a: partition into per-bucket regions — block-aggregated atomics.
// 1024 threads/block, 4096-edge chunk in registers; LDS histogram; ONE
// global atomicAdd per (block,bucket); cursors padded to 64B stride.
#define PART_CHUNK 4096
__global__ __launch_bounds__(1024) void k_partA(const int2* __restrict__ pk,
                                                int* __restrict__ bcursor,
                                                int2* __restrict__ stage, int E) {
    __shared__ int hist[NBUK];
    __shared__ int base[NBUK];
    int t = threadIdx.x;
    for (long long c0 = (long long)blockIdx.x * PART_CHUNK; c0 < E;
         c0 += (long long)gridDim.x * PART_CHUNK) {
        if (t < NBUK) hist[t] = 0;
        __syncthreads();
        int2 v[4];
        int b[4], r[4];
        #pragma unroll
        for (int j = 0; j < 4; j++) {
            long long e = c0 + j * 1024 + t;
            if (e < E) {
                v[j] = pk[e];
                b[j] = ((unsigned)v[j].x) >> 24;
            } else {
                b[j] = -1;
            }
        }
        #pragma unroll
        for (int j = 0; j < 4; j++)
            if (b[j] >= 0) r[j] = atomicAdd(&hist[b[j]], 1);
        __syncthreads();
        if (t < NBUK) {
            int h = hist[t];
            base[t] = h ? atomicAdd(&bcursor[t << 4], h) : 0;
        }
        __syncthreads();
        #pragma unroll
        for (int j = 0; j < 4; j++)
            if (b[j] >= 0) stage[base[b[j]] + r[j]] = v[j];
        __syncthreads();
    }
}

// K6b: one block per bucket; LDS rank atomics -> exact CSR position.
__global__ __launch_bounds__(256) void k_partB(const int* __restrict__ rstart,
                                               const int2* __restrict__ stage,
                                               int2* __restrict__ ep) {
    __shared__ int lcnt[256];
    __shared__ int lrs[256];
    int b = blockIdx.x, t = threadIdx.x;
    int dst0 = b << 8;
    int dst1 = min(dst0 + 256, N_NODES);
    lcnt[t] = 0;
    lrs[t] = rstart[min(dst0 + t, N_NODES)];
    __syncthreads();
    int base = rstart[dst0];
    int cnt = rstart[dst1] - base;
    for (int i = t; i < cnt; i += 256) {
        int2 v = stage[base + i];
        int dl = (v.x >> 16) & 255;
        int r = atomicAdd(&lcnt[dl], 1);
        ep[lrs[dl] + r] = make_int2(v.x & 0xFFFF, v.y);
    }
}

// ---------------------------------------------------------------------------
// K7: W[256][128] fp32 -> Wt[128][256] bf16 (transposed).
__global__ __launch_bounds__(256) void k_wconv(const float* __restrict__ W,
                                               short* __restrict__ Wt) {
    int id = blockIdx.x * 256 + threadIdx.x;
    if (id >= F_IN * F_OUT) return;
    int n = id >> 8;
    int k = id & 255;
    Wt[id] = f2bf(W[(size_t)k * F_OUT + n]);
}

// K8: H[M,128] = tanh(A[M,256] @ W) via bf16 MFMA, output fp16.
__global__ __launch_bounds__(256) void k_gemm_mfma(const float* __restrict__ A,
                                                   const short* __restrict__ Wt,
                                                   __half* __restrict__ H, int M) {
    int wave = threadIdx.x >> 6;
    int lane = threadIdx.x & 63;
    int lm = lane & 15;
    int kgrp = lane >> 4;
    int m = blockIdx.x * 64 + wave * 16 + lm;
    int am = (m < M) ? m : (M - 1);
    const float* arow = A + (size_t)am * F_IN + kgrp * 8;

    f32x4 acc[8] = {};

    for (int k0 = 0; k0 < F_IN; k0 += 32) {
        float4 a0 = *(const float4*)(arow + k0);
        float4 a1 = *(const float4*)(arow + k0 + 4);
        bf16x8 af;
        af[0] = f2bf(a0.x); af[1] = f2bf(a0.y);
        af[2] = f2bf(a0.z); af[3] = f2bf(a0.w);
        af[4] = f2bf(a1.x); af[5] = f2bf(a1.y);
        af[6] = f2bf(a1.z); af[7] = f2bf(a1.w);
        #pragma unroll
        for (int j = 0; j < 8; j++) {
            int col = j * 16 + lm;
            bf16x8 bf = *(const bf16x8*)(Wt + (size_t)col * F_IN + k0 + kgrp * 8);
            acc[j] = __builtin_amdgcn_mfma_f32_16x16x32_bf16(af, bf, acc[j], 0, 0, 0);
        }
    }

    int rbase = blockIdx.x * 64 + wave * 16 + kgrp * 4;
    #pragma unroll
    for (int j = 0; j < 8; j++) {
        #pragma unroll
        for (int jj = 0; jj < 4; jj++) {
            int r = rbase + jj;
            if (r < M)
                H[(size_t)r * F_OUT + j * 16 + lm] =
                    __float2half(fast_tanh(acc[j][jj]));
        }
    }
}

// ---------------------------------------------------------------------------
// K9: SPMM hop. One wave handles TWO nodes (interleaved gathers for ILP);
// lane owns cols {2*lane, 2*lane+1}. Per edge: 2 readlane + 2 v_dot2_f32_f16.
__global__ __launch_bounds__(256) void k_hop(const int* __restrict__ rstart,
                                             const int2* __restrict__ ep,
                                             const unsigned* __restrict__ xin,
                                             void* __restrict__ xoutv,
                                             const float* __restrict__ bias,
                                             int last) {
    int pair = blockIdx.x * 4 + (threadIdx.x >> 6);
    int widA = pair * 2;
    if (widA >= N_NODES) return;
    int widB = widA + 1;
    bool hasB = widB < N_NODES;
    int lane = threadIdx.x & 63;
    int sA = rstart[widA], eA = rstart[widA + 1];
    int sB = hasB ? rstart[widB] : 0;
    int eB = hasB ? rstart[widB + 1] : 0;
    float axA = 0.f, ayA = 0.f, axB = 0.f, ayB = 0.f;

#define EDGE(ev, j, ax, ay) {                                              \
        int sj = __builtin_amdgcn_readlane((ev).x, (j));                   \
        int wj = __builtin_amdgcn_readlane((ev).y, (j));                   \
        unsigned hv = xin[(size_t)sj * 64 + lane];                         \
        h2 h = u2h2(hv);                                                   \
        ax = __builtin_amdgcn_fdot2(h, u2h2((unsigned)wj), ax, false);     \
        ay = __builtin_amdgcn_fdot2(h, u2h2(((unsigned)wj) << 16), ay, false); }

    while (sA < eA || sB < eB) {
        int nA = eA - sA; nA = (nA > 64) ? 64 : (nA < 0 ? 0 : nA);
        int nB = eB - sB; nB = (nB > 64) ? 64 : (nB < 0 ? 0 : nB);
        int2 evA = (lane < nA) ? ep[sA + lane] : make_int2(0, 0);
        int2 evB = (lane < nB) ? ep[sB + lane] : make_int2(0, 0);
        int m = (nA < nB) ? nA : nB;
        int i = 0;
        for (; i + 2 <= m; i += 2) {
            EDGE(evA, i, axA, ayA)
            EDGE(evB, i, axB, ayB)
            EDGE(evA, i + 1, axA, ayA)
            EDGE(evB, i + 1, axB, ayB)
        }
        if (i < m) { EDGE(evA, i, axA, ayA) EDGE(evB, i, axB, ayB) i++; }
        for (int j = i; j < nA; j++) EDGE(evA, j, axA, ayA)
        for (int j = i; j < nB; j++) EDGE(evB, j, axB, ayB)
        sA += nA;
        sB += nB;
    }
#undef EDGE

    if (last) {
        float bx = bias[2 * lane], by = bias[2 * lane + 1];
        float2* o = (float2*)xoutv;
        o[(size_t)widA * 64 + lane] = make_float2(axA + bx, ayA + by);
        if (hasB) o[(size_t)widB * 64 + lane] = make_float2(axB + bx, ayB + by);
    } else {
        __half2* o = (__half2*)xoutv;
        o[(size_t)widA * 64 + lane] = __floats2half2_rn(axA, ayA);
        if (hasB) o[(size_t)widB * 64 + lane] = __floats2half2_rn(axB, ayB);
    }
}

// ---------------------------------------------------------------------------
extern "C" void kernel_launch(void* const* d_in, const int* in_sizes, int n_in,
                              void* d_out, int out_size, void* d_ws, size_t ws_size,
                              hipStream_t stream) {
    const float* features = (const float*)d_in[0];
    const float* weight   = (const float*)d_in[1];
    const float* bias     = (const float*)d_in[2];
    const void*  edge_idx = d_in[3];
    const float* edge_w   = (const float*)d_in[4];
    int E = in_sizes[4];
    float* out = (float*)d_out;

    char* ws = (char*)d_ws;
    size_t off = 0;
    auto alloc = [&](size_t bytes) -> void* {
        void* p = ws + off;
        off = (off + bytes + 255) & ~(size_t)255;
        return p;
    };
    int*    flag    = (int*)alloc(4);
    int*    counts  = (int*)alloc((size_t)N_NODES * 4);
    int*    rstart  = (int*)alloc((size_t)(N_NODES + 1) * 4);
    int*    bsums   = (int*)alloc(256 * 4);
    int*    boffs   = (int*)alloc(256 * 4);
    int*    bcursor = (int*)alloc(256 * 64);   // padded: 1 cursor per 64B
    int2*   pk      = (int2*)alloc((size_t)E * 8);
    int2*   stage   = (int2*)alloc((size_t)E * 8);
    int2*   ep      = (int2*)alloc((size_t)E * 8);
    short*  Wt      = (short*)alloc((size_t)F_IN * F_OUT * 2);
    __half* H0      = (__half*)alloc((size_t)N_NODES * F_OUT * 2);
    __half* H1      = (__half*)alloc((size_t)N_NODES * F_OUT * 2);

    hipMemsetAsync(counts, 0, (size_t)N_NODES * 4, stream);

    k_detect<<<1, 64, 0, stream>>>((const int*)edge_idx, flag);
    k_hist<<<(E + 255) / 256, 256, 0, stream>>>(edge_idx, edge_w, flag, pk,
                                                counts, E);
    int NB = (N_NODES + 255) / 256;  // 196
    k_scan1<<<NB, 256, 0, stream>>>(counts, rstart, bsums, N_NODES);
    k_scan2<<<1, 256, 0, stream>>>(bsums, boffs, NB);
    k_finish<<<NB, 256, 0, stream>>>(rstart, boffs, bcursor, N_NODES, E);
    int partBlocks = (E + PART_CHUNK - 1) / PART_CHUNK;  // 196
    k_partA<<<partBlocks, 1024, 0, stream>>>(pk, bcursor, stage, E);
    k_partB<<<NBUK, 256, 0, stream>>>(rstart, stage, ep);

    // H0 = tanh(features @ weight)  [bf16 MFMA, fp16 out]
    k_wconv<<<(F_IN * F_OUT + 255) / 256, 256, 0, stream>>>(weight, Wt);
    k_gemm_mfma<<<(N_NODES + 63) / 64, 256, 0, stream>>>(features, Wt, H0,
                                                         N_NODES);

    // 3 SPMM hops; last fuses +bias, writes fp32 d_out
    int hop_blocks = (25000 + 3) / 4;  // ceil(N/2) pairs, 4 waves/block
    k_hop<<<hop_blocks, 256, 0, stream>>>(rstart, ep, (const unsigned*)H0, H1,
                                          bias, 0);
    k_hop<<<hop_blocks, 256, 0, stream>>>(rstart, ep, (const unsigned*)H1, H0,
                                          bias, 0);
    k_hop<<<hop_blocks, 256, 0, stream>>>(rstart, ep, (const unsigned*)H0, out,
                                          bias, 1);
}

// Round 7
// 287.614 us; speedup vs baseline: 2.5633x; 1.0266x over previous
//
#include <hip/hip_runtime.h>
#include <hip/hip_bf16.h>
#include <hip/hip_fp16.h>
#include <math.h>

#define N_NODES 50000
#define F_IN 256
#define F_OUT 128
#define NBUK ((N_NODES + 255) >> 8)   // 196 buckets of 256 dsts

typedef __attribute__((ext_vector_type(8))) short bf16x8;
typedef __attribute__((ext_vector_type(4))) float f32x4;
typedef _Float16 h2 __attribute__((ext_vector_type(2)));

static __device__ __forceinline__ h2 u2h2(unsigned u) {
    union { unsigned u; h2 h; } x; x.u = u; return x.h;
}
static __device__ __forceinline__ short f2bf(float f) {
    unsigned u = __float_as_uint(f);
    unsigned r = (u + 0x7FFFu + ((u >> 16) & 1u)) >> 16;  // RNE
    return (short)r;
}
static __device__ __forceinline__ float fast_tanh(float x) {
    float e = __expf(2.0f * x);
    return 1.0f - 2.0f / (e + 1.0f);
}

// ---------------------------------------------------------------------------
// K1: detect int64 vs int32 edge_index layout.
__global__ __launch_bounds__(64) void k_detect(const int* __restrict__ ei,
                                               int* __restrict__ flag) {
    if (threadIdx.x == 0) {
        int orv = 0;
        for (int i = 0; i < 64; i++) orv |= ei[2 * i + 1];
        flag[0] = (orv == 0) ? 1 : 0;  // 1 => int64
    }
}

// K2: decode + pack {src | dstlow<<16 | bucket<<24, w_fp16} + dst histogram.
__global__ __launch_bounds__(256) void k_hist(const void* __restrict__ ei,
                                              const float* __restrict__ ew,
                                              const int* __restrict__ flag,
                                              int2* __restrict__ pk,
                                              int* __restrict__ counts, int E) {
    int e = blockIdx.x * 256 + threadIdx.x;
    if (e >= E) return;
    int s, d;
    if (flag[0]) {
        const long long* p = (const long long*)ei;
        s = (int)p[e];
        d = (int)p[(size_t)E + e];
    } else {
        const int* p = (const int*)ei;
        s = p[e];
        d = p[(size_t)E + e];
    }
    unsigned wh = __half_as_ushort(__float2half(ew[e]));
    pk[e] = make_int2(s | ((d & 255) << 16) | ((d >> 8) << 24), (int)wh);
    atomicAdd(&counts[d], 1);
}

// K3: per-block scan.
__global__ __launch_bounds__(256) void k_scan1(const int* __restrict__ counts,
                                               int* __restrict__ rstart,
                                               int* __restrict__ bsums, int n) {
    __shared__ int sh[256];
    int t = threadIdx.x;
    int i = blockIdx.x * 256 + t;
    int c = (i < n) ? counts[i] : 0;
    int val = c;
    sh[t] = val;
    __syncthreads();
    for (int off = 1; off < 256; off <<= 1) {
        int x = (t >= off) ? sh[t - off] : 0;
        __syncthreads();
        val += x;
        sh[t] = val;
        __syncthreads();
    }
    if (i < n) rstart[i] = val - c;
    if (t == 255) bsums[blockIdx.x] = val;
}

// K4: scan of block sums (NB <= 256).
__global__ __launch_bounds__(256) void k_scan2(const int* __restrict__ bsums,
                                               int* __restrict__ boffs, int n) {
    __shared__ int sh[256];
    int t = threadIdx.x;
    int c = (t < n) ? bsums[t] : 0;
    int val = c;
    sh[t] = val;
    __syncthreads();
    for (int off = 1; off < 256; off <<= 1) {
        int x = (t >= off) ? sh[t - off] : 0;
        __syncthreads();
        val += x;
        sh[t] = val;
        __syncthreads();
    }
    if (t < n) boffs[t] = val - c;
}

// K5: finalize row_start; bucket cursor (padded: 1 per 64B line).
__global__ __launch_bounds__(256) void k_finish(int* __restrict__ rstart,
                                                const int* __restrict__ boffs,
                                                int* __restrict__ bcursor,
                                                int n, int E) {
    int i = blockIdx.x * 256 + threadIdx.x;
    if (i < n) {
        int v = rstart[i] + boffs[i >> 8];
        rstart[i] = v;
        if ((i & 255) == 0) bcursor[(i >> 8) << 4] = v;
    }
    if (blockIdx.x == 0 && threadIdx.x == 0) rstart[n] = E;
}

// K6a: partition into per-bucket regions — block-aggregated atomics.
#define PART_CHUNK 4096
__global__ __launch_bounds__(1024) void k_partA(const int2* __restrict__ pk,
                                                int* __restrict__ bcursor,
                                                int2* __restrict__ stage, int E) {
    __shared__ int hist[NBUK];
    __shared__ int base[NBUK];
    int t = threadIdx.x;
    for (long long c0 = (long long)blockIdx.x * PART_CHUNK; c0 < E;
         c0 += (long long)gridDim.x * PART_CHUNK) {
        if (t < NBUK) hist[t] = 0;
        __syncthreads();
        int2 v[4];
        int b[4], r[4];
        #pragma unroll
        for (int j = 0; j < 4; j++) {
            long long e = c0 + j * 1024 + t;
            if (e < E) {
                v[j] = pk[e];
                b[j] = ((unsigned)v[j].x) >> 24;
            } else {
                b[j] = -1;
            }
        }
        #pragma unroll
        for (int j = 0; j < 4; j++)
            if (b[j] >= 0) r[j] = atomicAdd(&hist[b[j]], 1);
        __syncthreads();
        if (t < NBUK) {
            int h = hist[t];
            base[t] = h ? atomicAdd(&bcursor[t << 4], h) : 0;
        }
        __syncthreads();
        #pragma unroll
        for (int j = 0; j < 4; j++)
            if (b[j] >= 0) stage[base[b[j]] + r[j]] = v[j];
        __syncthreads();
    }
}

// K6b: one block per bucket; LDS rank atomics -> exact CSR position.
__global__ __launch_bounds__(256) void k_partB(const int* __restrict__ rstart,
                                               const int2* __restrict__ stage,
                                               int2* __restrict__ ep) {
    __shared__ int lcnt[256];
    __shared__ int lrs[256];
    int b = blockIdx.x, t = threadIdx.x;
    int dst0 = b << 8;
    int dst1 = min(dst0 + 256, N_NODES);
    lcnt[t] = 0;
    lrs[t] = rstart[min(dst0 + t, N_NODES)];
    __syncthreads();
    int base = rstart[dst0];
    int cnt = rstart[dst1] - base;
    for (int i = t; i < cnt; i += 256) {
        int2 v = stage[base + i];
        int dl = (v.x >> 16) & 255;
        int r = atomicAdd(&lcnt[dl], 1);
        ep[lrs[dl] + r] = make_int2(v.x & 0xFFFF, v.y);
    }
}

// ---------------------------------------------------------------------------
// K7: W[256][128] fp32 -> Wt[128][256] bf16 (transposed).
__global__ __launch_bounds__(256) void k_wconv(const float* __restrict__ W,
                                               short* __restrict__ Wt) {
    int id = blockIdx.x * 256 + threadIdx.x;
    if (id >= F_IN * F_OUT) return;
    int n = id >> 8;
    int k = id & 255;
    Wt[id] = f2bf(W[(size_t)k * F_OUT + n]);
}

// K8: H[M,128] = tanh(A[M,256] @ W) via bf16 MFMA, fp16 out.
// K-split 2-way: block = 4 waves over 32 rows; waves (rowhalf,khalf).
// Each wave prefetches its ENTIRE A strip (8 float4, independent loads) up
// front for memory-level parallelism, then 4 k0-steps x 8 MFMA.
// khalf=1 waves dump acc to LDS (stride 36 dwords: 16B-aligned, uniform
// 8-lane/bank); khalf=0 waves add + tanh + store.
#define RED_STRIDE 36
__global__ __launch_bounds__(256) void k_gemm_mfma(const float* __restrict__ A,
                                                   const short* __restrict__ Wt,
                                                   __half* __restrict__ H, int M) {
    __shared__ float red[2 * 64 * RED_STRIDE];  // 18.4 KB
    int wave = threadIdx.x >> 6;
    int lane = threadIdx.x & 63;
    int lm = lane & 15;
    int kgrp = lane >> 4;
    int rowhalf = wave >> 1;
    int khalf = wave & 1;
    int m = blockIdx.x * 32 + rowhalf * 16 + lm;
    int am = (m < M) ? m : (M - 1);
    const float* arow = A + (size_t)am * F_IN + khalf * 128 + kgrp * 8;

    float4 a[8];
    #pragma unroll
    for (int k0 = 0; k0 < 4; k0++) {
        a[2 * k0]     = *(const float4*)(arow + k0 * 32);
        a[2 * k0 + 1] = *(const float4*)(arow + k0 * 32 + 4);
    }

    f32x4 acc[8] = {};
    #pragma unroll
    for (int k0 = 0; k0 < 4; k0++) {
        bf16x8 af;
        af[0] = f2bf(a[2 * k0].x);     af[1] = f2bf(a[2 * k0].y);
        af[2] = f2bf(a[2 * k0].z);     af[3] = f2bf(a[2 * k0].w);
        af[4] = f2bf(a[2 * k0 + 1].x); af[5] = f2bf(a[2 * k0 + 1].y);
        af[6] = f2bf(a[2 * k0 + 1].z); af[7] = f2bf(a[2 * k0 + 1].w);
        int koff = khalf * 128 + k0 * 32 + kgrp * 8;
        #pragma unroll
        for (int j = 0; j < 8; j++) {
            bf16x8 bf = *(const bf16x8*)(Wt + (size_t)(j * 16 + lm) * F_IN + koff);
            acc[j] = __builtin_amdgcn_mfma_f32_16x16x32_bf16(af, bf, acc[j], 0, 0, 0);
        }
    }

    float* myred = &red[(rowhalf * 64 + lane) * RED_STRIDE];
    if (khalf == 1) {
        #pragma unroll
        for (int j = 0; j < 8; j++) *(f32x4*)(myred + j * 4) = acc[j];
    }
    __syncthreads();
    if (khalf == 0) {
        int rbase = blockIdx.x * 32 + rowhalf * 16 + kgrp * 4;
        #pragma unroll
        for (int j = 0; j < 8; j++) {
            f32x4 o = *(const f32x4*)(myred + j * 4);
            #pragma unroll
            for (int jj = 0; jj < 4; jj++) {
                int r = rbase + jj;
                if (r < M)
                    H[(size_t)r * F_OUT + j * 16 + lm] =
                        __float2half(fast_tanh(acc[j][jj] + o[jj]));
            }
        }
    }
}

// ---------------------------------------------------------------------------
// K9: SPMM hop. Wave handles 2 nodes; lane owns cols {2l, 2l+1}.
// 4x unroll per node: 8 independent row-gathers issued before the 16 dot2s.
__global__ __launch_bounds__(256) void k_hop(const int* __restrict__ rstart,
                                             const int2* __restrict__ ep,
                                             const unsigned* __restrict__ xin,
                                             void* __restrict__ xoutv,
                                             const float* __restrict__ bias,
                                             int last) {
    int pair = blockIdx.x * 4 + (threadIdx.x >> 6);
    int widA = pair * 2;
    if (widA >= N_NODES) return;
    int widB = widA + 1;
    bool hasB = widB < N_NODES;
    int lane = threadIdx.x & 63;
    int sA = rstart[widA], eA = rstart[widA + 1];
    int sB = hasB ? rstart[widB] : 0;
    int eB = hasB ? rstart[widB + 1] : 0;
    float axA = 0.f, ayA = 0.f, axB = 0.f, ayB = 0.f;

#define GATHER(ev, j) \
    xin[(size_t)(unsigned)__builtin_amdgcn_readlane((ev).x, (j)) * 64 + lane]
#define DOT(hv, wj, ax, ay) {                                               \
        h2 h_ = u2h2(hv);                                                   \
        ax = __builtin_amdgcn_fdot2(h_, u2h2((unsigned)(wj)), ax, false);   \
        ay = __builtin_amdgcn_fdot2(h_, u2h2(((unsigned)(wj)) << 16), ay, false); }
#define EDGE1(ev, j, ax, ay) {                                              \
        unsigned hv_ = GATHER(ev, j);                                       \
        int wj_ = __builtin_amdgcn_readlane((ev).y, (j));                   \
        DOT(hv_, wj_, ax, ay) }

    while (sA < eA || sB < eB) {
        int nA = eA - sA; nA = (nA > 64) ? 64 : (nA < 0 ? 0 : nA);
        int nB = eB - sB; nB = (nB > 64) ? 64 : (nB < 0 ? 0 : nB);
        int2 evA = (lane < nA) ? ep[sA + lane] : make_int2(0, 0);
        int2 evB = (lane < nB) ? ep[sB + lane] : make_int2(0, 0);
        int m = (nA < nB) ? nA : nB;
        int i = 0;
        for (; i + 4 <= m; i += 4) {
            // issue 8 independent gathers
            unsigned va0 = GATHER(evA, i);
            unsigned va1 = GATHER(evA, i + 1);
            unsigned va2 = GATHER(evA, i + 2);
            unsigned va3 = GATHER(evA, i + 3);
            unsigned vb0 = GATHER(evB, i);
            unsigned vb1 = GATHER(evB, i + 1);
            unsigned vb2 = GATHER(evB, i + 2);
            unsigned vb3 = GATHER(evB, i + 3);
            int wa0 = __builtin_amdgcn_readlane(evA.y, i);
            int wa1 = __builtin_amdgcn_readlane(evA.y, i + 1);
            int wa2 = __builtin_amdgcn_readlane(evA.y, i + 2);
            int wa3 = __builtin_amdgcn_readlane(evA.y, i + 3);
            int wb0 = __builtin_amdgcn_readlane(evB.y, i);
            int wb1 = __builtin_amdgcn_readlane(evB.y, i + 1);
            int wb2 = __builtin_amdgcn_readlane(evB.y, i + 2);
            int wb3 = __builtin_amdgcn_readlane(evB.y, i + 3);
            DOT(va0, wa0, axA, ayA)
            DOT(va1, wa1, axA, ayA)
            DOT(va2, wa2, axA, ayA)
            DOT(va3, wa3, axA, ayA)
            DOT(vb0, wb0, axB, ayB)
            DOT(vb1, wb1, axB, ayB)
            DOT(vb2, wb2, axB, ayB)
            DOT(vb3, wb3, axB, ayB)
        }
        for (; i < m; i++) { EDGE1(evA, i, axA, ayA) EDGE1(evB, i, axB, ayB) }
        for (int j = i; j < nA; j++) EDGE1(evA, j, axA, ayA)
        for (int j = i; j < nB; j++) EDGE1(evB, j, axB, ayB)
        sA += nA;
        sB += nB;
    }
#undef EDGE1
#undef DOT
#undef GATHER

    if (last) {
        float bx = bias[2 * lane], by = bias[2 * lane + 1];
        float2* o = (float2*)xoutv;
        o[(size_t)widA * 64 + lane] = make_float2(axA + bx, ayA + by);
        if (hasB) o[(size_t)widB * 64 + lane] = make_float2(axB + bx, ayB + by);
    } else {
        __half2* o = (__half2*)xoutv;
        o[(size_t)widA * 64 + lane] = __floats2half2_rn(axA, ayA);
        if (hasB) o[(size_t)widB * 64 + lane] = __floats2half2_rn(axB, ayB);
    }
}

// ---------------------------------------------------------------------------
extern "C" void kernel_launch(void* const* d_in, const int* in_sizes, int n_in,
                              void* d_out, int out_size, void* d_ws, size_t ws_size,
                              hipStream_t stream) {
    const float* features = (const float*)d_in[0];
    const float* weight   = (const float*)d_in[1];
    const float* bias     = (const float*)d_in[2];
    const void*  edge_idx = d_in[3];
    const float* edge_w   = (const float*)d_in[4];
    int E = in_sizes[4];
    float* out = (float*)d_out;

    char* ws = (char*)d_ws;
    size_t off = 0;
    auto alloc = [&](size_t bytes) -> void* {
        void* p = ws + off;
        off = (off + bytes + 255) & ~(size_t)255;
        return p;
    };
    int*    flag    = (int*)alloc(4);
    int*    counts  = (int*)alloc((size_t)N_NODES * 4);
    int*    rstart  = (int*)alloc((size_t)(N_NODES + 1) * 4);
    int*    bsums   = (int*)alloc(256 * 4);
    int*    boffs   = (int*)alloc(256 * 4);
    int*    bcursor = (int*)alloc(256 * 64);   // padded: 1 cursor per 64B
    int2*   pk      = (int2*)alloc((size_t)E * 8);
    int2*   stage   = (int2*)alloc((size_t)E * 8);
    int2*   ep      = (int2*)alloc((size_t)E * 8);
    short*  Wt      = (short*)alloc((size_t)F_IN * F_OUT * 2);
    __half* H0      = (__half*)alloc((size_t)N_NODES * F_OUT * 2);
    __half* H1      = (__half*)alloc((size_t)N_NODES * F_OUT * 2);

    hipMemsetAsync(counts, 0, (size_t)N_NODES * 4, stream);

    k_detect<<<1, 64, 0, stream>>>((const int*)edge_idx, flag);
    k_hist<<<(E + 255) / 256, 256, 0, stream>>>(edge_idx, edge_w, flag, pk,
                                                counts, E);
    int NB = (N_NODES + 255) / 256;  // 196
    k_scan1<<<NB, 256, 0, stream>>>(counts, rstart, bsums, N_NODES);
    k_scan2<<<1, 256, 0, stream>>>(bsums, boffs, NB);
    k_finish<<<NB, 256, 0, stream>>>(rstart, boffs, bcursor, N_NODES, E);
    int partBlocks = (E + PART_CHUNK - 1) / PART_CHUNK;  // 196
    k_partA<<<partBlocks, 1024, 0, stream>>>(pk, bcursor, stage, E);
    k_partB<<<NBUK, 256, 0, stream>>>(rstart, stage, ep);

    // H0 = tanh(features @ weight)  [bf16 MFMA, K-split, fp16 out]
    k_wconv<<<(F_IN * F_OUT + 255) / 256, 256, 0, stream>>>(weight, Wt);
    k_gemm_mfma<<<(N_NODES + 31) / 32, 256, 0, stream>>>(features, Wt, H0,
                                                         N_NODES);

    // 3 SPMM hops; last fuses +bias, writes fp32 d_out
    int hop_blocks = (25000 + 3) / 4;  // ceil(N/2) pairs, 4 waves/block
    k_hop<<<hop_blocks, 256, 0, stream>>>(rstart, ep, (const unsigned*)H0, H1,
                                          bias, 0);
    k_hop<<<hop_blocks, 256, 0, stream>>>(rstart, ep, (const unsigned*)H1, H0,
                                          bias, 0);
    k_hop<<<hop_blocks, 256, 0, stream>>>(rstart, ep, (const unsigned*)H0, out,
                                          bias, 1);
}